// Round 11
// baseline (1095.097 us; speedup 1.0000x reference)
//
#include <hip/hip_runtime.h>

// NodeModel: agg = segment_sum(x[row], col); h = concat(x, agg); out = MLP(h).
//
// Path A (full CSC, zero-atomic agg):
//   0) pad x -> x4 (float4/node).
//   1) counting-sort by col-bucket (col>>12, 245 cursors = proven safe);
//      payload (row<<12)|col_local.
//   2) reorder_col: per bucket, 4096-bin counting sort by col_local ->
//      packed3 (= rows, globally col-sorted = CSC adjacency) and global
//      colStart[] per-node offsets (from the in-LDS scan, free).
//   3) agg_csc_mlp: ONE THREAD PER NODE: serially sum x4[row] over its
//      contiguous edge run into registers (no atomics, no LDS acc, no
//      waitcnt->atomic chains), apply MLP inline, store. This removes the
//      78M LDS atomicAdds that rounds 3/7/10 showed to be the invariant
//      ~425us cost regardless of memory traffic.
// Path B (smaller ws): col-bucket sort + LDS-atomic agg (round-3, 728us).
// Path C: global atomicAdd + separate MLP.

#define SH    12
#define TILE  4096            // nodes per col-bucket
#define MAXNB 256
#define NBLK  512             // edge chunks for hist/scatter
#define THR   1024

// ---------------- sort kernels ----------------

__global__ __launch_bounds__(THR) void hist_kernel(
    const int* __restrict__ key, int* __restrict__ hist,
    int nb, int chunk, int n_edges)
{
    __shared__ int lh[MAXNB];
    const int t = threadIdx.x, b = blockIdx.x;
    for (int k = t; k < nb; k += THR) lh[k] = 0;
    __syncthreads();

    long long s = (long long)b * chunk;
    long long e = s + chunk; if (e > n_edges) e = n_edges;
    if (s < e) {
        const int n = (int)(e - s);
        const int n4 = n >> 2;
        const int4* __restrict__ k4p = reinterpret_cast<const int4*>(key + s);
        for (int i = t; i < n4; i += THR) {
            int4 c = k4p[i];
            atomicAdd(&lh[(unsigned)c.x >> SH], 1);
            atomicAdd(&lh[(unsigned)c.y >> SH], 1);
            atomicAdd(&lh[(unsigned)c.z >> SH], 1);
            atomicAdd(&lh[(unsigned)c.w >> SH], 1);
        }
        for (int i = (n4 << 2) + t; i < n; i += THR)
            atomicAdd(&lh[(unsigned)key[s + i] >> SH], 1);
    }
    __syncthreads();
    for (int k = t; k < nb; k += THR) hist[(size_t)b * nb + k] = lh[k];
}

__global__ __launch_bounds__(NBLK) void scan_blocks_kernel(
    int* __restrict__ hist, int* __restrict__ keyTotal, int nb)
{
    __shared__ int sd[NBLK];
    const int t = threadIdx.x, k = blockIdx.x;
    const int v = hist[(size_t)t * nb + k];
    sd[t] = v; __syncthreads();
#pragma unroll
    for (int off = 1; off < NBLK; off <<= 1) {
        int a = (t >= off) ? sd[t - off] : 0;
        __syncthreads();
        sd[t] += a;
        __syncthreads();
    }
    hist[(size_t)t * nb + k] = sd[t] - v;
    if (t == NBLK - 1) keyTotal[k] = sd[t];
}

__global__ __launch_bounds__(1024) void scan_keys_kernel(
    const int* __restrict__ keyTotal, int* __restrict__ keyStart, int nb)
{
    __shared__ int sd[1024];
    const int t = threadIdx.x;
    const int v = (t < nb) ? keyTotal[t] : 0;
    sd[t] = v; __syncthreads();
#pragma unroll
    for (int off = 1; off < 1024; off <<= 1) {
        int a = (t >= off) ? sd[t - off] : 0;
        __syncthreads();
        sd[t] += a;
        __syncthreads();
    }
    if (t < nb) keyStart[t] = sd[t] - v;
    if (t == 0) keyStart[nb] = sd[1023];
}

__global__ __launch_bounds__(THR) void scatter_kernel(
    const int* __restrict__ key, const int* __restrict__ other,
    const int* __restrict__ hist, const int* __restrict__ keyStart,
    unsigned* __restrict__ packed, int nb, int chunk, int n_edges)
{
    __shared__ int lc[MAXNB];
    const int t = threadIdx.x, b = blockIdx.x;
    for (int k = t; k < nb; k += THR)
        lc[k] = keyStart[k] + hist[(size_t)b * nb + k];
    __syncthreads();

    long long s = (long long)b * chunk;
    long long e = s + chunk; if (e > n_edges) e = n_edges;
    if (s < e) {
        const int n = (int)(e - s);
        const int n4 = n >> 2;
        const int4* __restrict__ k4p = reinterpret_cast<const int4*>(key + s);
        const int4* __restrict__ o4p = reinterpret_cast<const int4*>(other + s);
        for (int i = t; i < n4; i += THR) {
            int4 c = k4p[i];
            int4 r = o4p[i];
            int p;
            p = atomicAdd(&lc[(unsigned)c.x >> SH], 1);
            packed[p] = ((unsigned)r.x << SH) | ((unsigned)c.x & (TILE - 1));
            p = atomicAdd(&lc[(unsigned)c.y >> SH], 1);
            packed[p] = ((unsigned)r.y << SH) | ((unsigned)c.y & (TILE - 1));
            p = atomicAdd(&lc[(unsigned)c.z >> SH], 1);
            packed[p] = ((unsigned)r.z << SH) | ((unsigned)c.z & (TILE - 1));
            p = atomicAdd(&lc[(unsigned)c.w >> SH], 1);
            packed[p] = ((unsigned)r.w << SH) | ((unsigned)c.w & (TILE - 1));
        }
        for (int i = (n4 << 2) + t; i < n; i += THR) {
            int c = key[s + i], r = other[s + i];
            int p = atomicAdd(&lc[(unsigned)c >> SH], 1);
            packed[p] = ((unsigned)r << SH) | ((unsigned)c & (TILE - 1));
        }
    }
}

// ---------------- x padding ----------------

__global__ __launch_bounds__(256) void pad_x_kernel(
    const float* __restrict__ x, float4* __restrict__ x4, int n)
{
    const int stride = gridDim.x * 256;
    for (int i = blockIdx.x * 256 + threadIdx.x; i < n; i += stride) {
        float4 v;
        v.x = x[3 * i + 0];
        v.y = x[3 * i + 1];
        v.z = x[3 * i + 2];
        v.w = 0.0f;
        x4[i] = v;
    }
}

// ------ per-bucket 4096-bin counting sort by col_local -> CSC ------------

__global__ __launch_bounds__(THR) void reorder_col_kernel(
    const unsigned* __restrict__ packed, unsigned* __restrict__ packed3,
    const int* __restrict__ keyStart, int* __restrict__ colStart,
    int nb, int n_edges)
{
    __shared__ int h[TILE];       // 16 KB: histogram, then absolute cursors
    __shared__ int tsum[THR];     //  4 KB
    const int t = threadIdx.x, cb = blockIdx.x;

#pragma unroll
    for (int k = t; k < TILE; k += THR) h[k] = 0;
    __syncthreads();

    const int s = keyStart[cb], e = keyStart[cb + 1];

    // pass 1: histogram of col_local
    {
        int s4 = (s + 3) & ~3; if (s4 > e) s4 = e;
        const int e4 = s4 + ((e - s4) & ~3);
        const uint4* __restrict__ p4p = reinterpret_cast<const uint4*>(packed);
        for (int i = s + t; i < s4; i += THR) atomicAdd(&h[packed[i] & (TILE - 1)], 1);
        for (int i = e4 + t; i < e; i += THR) atomicAdd(&h[packed[i] & (TILE - 1)], 1);
        for (int i = (s4 >> 2) + t; i < (e4 >> 2); i += THR) {
            uint4 p = p4p[i];
            atomicAdd(&h[p.x & (TILE - 1)], 1);
            atomicAdd(&h[p.y & (TILE - 1)], 1);
            atomicAdd(&h[p.z & (TILE - 1)], 1);
            atomicAdd(&h[p.w & (TILE - 1)], 1);
        }
    }
    __syncthreads();

    // scan: thread t owns bins [4t, 4t+4)
    const int b0 = h[4 * t + 0];
    const int b1 = h[4 * t + 1];
    const int b2 = h[4 * t + 2];
    const int b3 = h[4 * t + 3];
    const int tot = b0 + b1 + b2 + b3;
    tsum[t] = tot;
    __syncthreads();
#pragma unroll
    for (int off = 1; off < THR; off <<= 1) {
        int a = (t >= off) ? tsum[t - off] : 0;
        __syncthreads();
        tsum[t] += a;
        __syncthreads();
    }
    const int base = s + tsum[t] - tot;   // exclusive + segment base

    // absolute cursors into h; emit global colStart
    const int c0 = base;
    const int c1 = c0 + b0;
    const int c2 = c1 + b1;
    const int c3 = c2 + b2;
    h[4 * t + 0] = c0;
    h[4 * t + 1] = c1;
    h[4 * t + 2] = c2;
    h[4 * t + 3] = c3;
    int* __restrict__ cs = colStart + (size_t)cb * TILE;
    cs[4 * t + 0] = c0;
    cs[4 * t + 1] = c1;
    cs[4 * t + 2] = c2;
    cs[4 * t + 3] = c3;
    if (cb == nb - 1 && t == 0) colStart[(size_t)nb * TILE] = n_edges;
    __syncthreads();

    // pass 2: scatter rows into col-sorted positions
    {
        int s4 = (s + 3) & ~3; if (s4 > e) s4 = e;
        const int e4 = s4 + ((e - s4) & ~3);
        const uint4* __restrict__ p4p = reinterpret_cast<const uint4*>(packed);
        for (int i = s + t; i < s4; i += THR) {
            unsigned p = packed[i];
            int q = atomicAdd(&h[p & (TILE - 1)], 1);
            packed3[q] = p >> SH;
        }
        for (int i = e4 + t; i < e; i += THR) {
            unsigned p = packed[i];
            int q = atomicAdd(&h[p & (TILE - 1)], 1);
            packed3[q] = p >> SH;
        }
        for (int i = (s4 >> 2) + t; i < (e4 >> 2); i += THR) {
            uint4 p = p4p[i];
            int q0 = atomicAdd(&h[p.x & (TILE - 1)], 1);
            packed3[q0] = p.x >> SH;
            int q1 = atomicAdd(&h[p.y & (TILE - 1)], 1);
            packed3[q1] = p.y >> SH;
            int q2 = atomicAdd(&h[p.z & (TILE - 1)], 1);
            packed3[q2] = p.z >> SH;
            int q3 = atomicAdd(&h[p.w & (TILE - 1)], 1);
            packed3[q3] = p.w >> SH;
        }
    }
}

// ---------- CSC agg: one thread per node, register accumulation ----------

__global__ __launch_bounds__(256) void agg_csc_mlp_kernel(
    const unsigned* __restrict__ packed3, const float4* __restrict__ x4,
    const float* __restrict__ x, const int* __restrict__ colStart,
    const float* __restrict__ W1, const float* __restrict__ b1,
    const float* __restrict__ W2, const float* __restrict__ b2,
    const float* __restrict__ W3, const float* __restrict__ b3,
    float* __restrict__ out, int n_nodes)
{
    __shared__ float sW1[96], sb1[16], sW2[256], sb2[16], sW3[48], sb3[3];
    const int t = threadIdx.x;
    if (t < 96)  sW1[t] = W1[t];
    if (t < 16)  sb1[t] = b1[t];
    sW2[t] = W2[t];
    if (t < 16)  sb2[t] = b2[t];
    if (t < 48)  sW3[t] = W3[t];
    if (t < 3)   sb3[t] = b3[t];
    __syncthreads();

    const int j = blockIdx.x * 256 + t;
    if (j >= n_nodes) return;

    const int s = colStart[j];
    const int e = colStart[j + 1];

    float a0 = 0.0f, a1 = 0.0f, a2 = 0.0f;
    float c0 = 0.0f, c1 = 0.0f, c2 = 0.0f;
    int i = s;
    for (; i + 1 < e; i += 2) {
        unsigned r0 = packed3[i];
        unsigned r1 = packed3[i + 1];
        float4 v0 = x4[r0];
        float4 v1 = x4[r1];
        a0 += v0.x; a1 += v0.y; a2 += v0.z;
        c0 += v1.x; c1 += v1.y; c2 += v1.z;
    }
    if (i < e) {
        float4 v = x4[packed3[i]];
        a0 += v.x; a1 += v.y; a2 += v.z;
    }
    a0 += c0; a1 += c1; a2 += c2;

    float in6[6];
    in6[0] = x[3 * j + 0];
    in6[1] = x[3 * j + 1];
    in6[2] = x[3 * j + 2];
    in6[3] = a0;
    in6[4] = a1;
    in6[5] = a2;

    float h1[16];
#pragma unroll
    for (int q = 0; q < 16; ++q) {
        float sv = sb1[q];
#pragma unroll
        for (int r = 0; r < 6; ++r) sv = fmaf(in6[r], sW1[r * 16 + q], sv);
        h1[q] = fmaxf(sv, 0.0f);
    }
    float h2[16];
#pragma unroll
    for (int q = 0; q < 16; ++q) {
        float sv = sb2[q];
#pragma unroll
        for (int r = 0; r < 16; ++r) sv = fmaf(h1[r], sW2[r * 16 + q], sv);
        h2[q] = fmaxf(sv, 0.0f);
    }
    float o0 = sb3[0], o1 = sb3[1], o2 = sb3[2];
#pragma unroll
    for (int q = 0; q < 16; ++q) {
        o0 = fmaf(h2[q], sW3[q * 3 + 0], o0);
        o1 = fmaf(h2[q], sW3[q * 3 + 1], o1);
        o2 = fmaf(h2[q], sW3[q * 3 + 2], o2);
    }
    out[3 * j + 0] = o0;
    out[3 * j + 1] = o1;
    out[3 * j + 2] = o2;
}

// ---------------- Path B: LDS-atomic agg + fused MLP (round-3) ----------

__global__ __launch_bounds__(THR) void bucket_agg_mlp_kernel(
    const unsigned* __restrict__ packed, const float* __restrict__ x,
    const int* __restrict__ keyStart,
    const float* __restrict__ W1, const float* __restrict__ b1,
    const float* __restrict__ W2, const float* __restrict__ b2,
    const float* __restrict__ W3, const float* __restrict__ b3,
    float* __restrict__ out, int n_nodes)
{
    __shared__ float acc[TILE * 3];
    __shared__ float sW1[96], sb1[16], sW2[256], sb2[16], sW3[48], sb3[3];
    const int t = threadIdx.x, k = blockIdx.x;

    if (t < 96)  sW1[t] = W1[t];
    if (t < 16)  sb1[t] = b1[t];
    if (t < 256) sW2[t] = W2[t];
    if (t >= 256 && t < 272) sb2[t - 256] = b2[t - 256];
    if (t >= 272 && t < 320) sW3[t - 272] = W3[t - 272];
    if (t >= 320 && t < 323) sb3[t - 320] = b3[t - 320];
    for (int f = t; f < TILE * 3; f += THR) acc[f] = 0.0f;
    __syncthreads();

    const int s = keyStart[k];
    const int e = keyStart[k + 1];
    for (int i = s + t; i < e; i += THR) {
        const unsigned p = packed[i];
        const float* __restrict__ xs = x + 3ll * (p >> SH);
        const int j = (int)(p & (TILE - 1)) * 3;
        atomicAdd(&acc[j + 0], xs[0]);
        atomicAdd(&acc[j + 1], xs[1]);
        atomicAdd(&acc[j + 2], xs[2]);
    }
    __syncthreads();

    const long long base = (long long)k << SH;
    long long lim = (long long)n_nodes - base;
    if (lim > TILE) lim = TILE;
    if (lim <= 0) return;

    for (int j = t; j < (int)lim; j += THR) {
        const long long node = base + j;
        float in6[6];
        in6[0] = x[3 * node + 0];
        in6[1] = x[3 * node + 1];
        in6[2] = x[3 * node + 2];
        in6[3] = acc[3 * j + 0];
        in6[4] = acc[3 * j + 1];
        in6[5] = acc[3 * j + 2];

        float h1[16];
#pragma unroll
        for (int q = 0; q < 16; ++q) {
            float sv = sb1[q];
#pragma unroll
            for (int r = 0; r < 6; ++r) sv = fmaf(in6[r], sW1[r * 16 + q], sv);
            h1[q] = fmaxf(sv, 0.0f);
        }
        float h2[16];
#pragma unroll
        for (int q = 0; q < 16; ++q) {
            float sv = sb2[q];
#pragma unroll
            for (int r = 0; r < 16; ++r) sv = fmaf(h1[r], sW2[r * 16 + q], sv);
            h2[q] = fmaxf(sv, 0.0f);
        }
        float o0 = sb3[0], o1 = sb3[1], o2 = sb3[2];
#pragma unroll
        for (int q = 0; q < 16; ++q) {
            o0 = fmaf(h2[q], sW3[q * 3 + 0], o0);
            o1 = fmaf(h2[q], sW3[q * 3 + 1], o1);
            o2 = fmaf(h2[q], sW3[q * 3 + 2], o2);
        }
        out[3 * node + 0] = o0;
        out[3 * node + 1] = o1;
        out[3 * node + 2] = o2;
    }
}

// ---------------- Path C ----------------

__global__ __launch_bounds__(256) void edge_scatter_kernel(
    const int* __restrict__ rows, const int* __restrict__ cols,
    const float* __restrict__ x, float* __restrict__ agg, int n_edges)
{
    const long long tid = (long long)blockIdx.x * blockDim.x + threadIdx.x;
    const long long stride = (long long)gridDim.x * blockDim.x;
    for (long long i = tid; i < n_edges; i += stride) {
        int r = rows[i], c = cols[i];
        const float* xs = x + 3ll * r; float* a = agg + 3ll * c;
        atomicAdd(a + 0, xs[0]); atomicAdd(a + 1, xs[1]); atomicAdd(a + 2, xs[2]);
    }
}

__global__ __launch_bounds__(256) void node_mlp_kernel(
    const float* __restrict__ x,
    const float* __restrict__ W1, const float* __restrict__ b1,
    const float* __restrict__ W2, const float* __restrict__ b2,
    const float* __restrict__ W3, const float* __restrict__ b3,
    float* __restrict__ out, int n_nodes)
{
    __shared__ float sW1[96], sb1[16], sW2[256], sb2[16], sW3[48], sb3[3];
    const int t = threadIdx.x;
    if (t < 96)  sW1[t] = W1[t];
    if (t < 16)  sb1[t] = b1[t];
    sW2[t] = W2[t];
    if (t < 16)  sb2[t] = b2[t];
    if (t < 48)  sW3[t] = W3[t];
    if (t < 3)   sb3[t] = b3[t];
    __syncthreads();

    const int i = blockIdx.x * 256 + t;
    if (i >= n_nodes) return;

    float in6[6];
    in6[0] = x[3 * i + 0];
    in6[1] = x[3 * i + 1];
    in6[2] = x[3 * i + 2];
    in6[3] = out[3 * i + 0];
    in6[4] = out[3 * i + 1];
    in6[5] = out[3 * i + 2];

    float h1[16];
#pragma unroll
    for (int j = 0; j < 16; ++j) {
        float s = sb1[j];
#pragma unroll
        for (int k = 0; k < 6; ++k) s = fmaf(in6[k], sW1[k * 16 + j], s);
        h1[j] = fmaxf(s, 0.0f);
    }
    float h2[16];
#pragma unroll
    for (int j = 0; j < 16; ++j) {
        float s = sb2[j];
#pragma unroll
        for (int k = 0; k < 16; ++k) s = fmaf(h1[k], sW2[k * 16 + j], s);
        h2[j] = fmaxf(s, 0.0f);
    }
    float o[3];
#pragma unroll
    for (int c = 0; c < 3; ++c) {
        float s = sb3[c];
#pragma unroll
        for (int j = 0; j < 16; ++j) s = fmaf(h2[j], sW3[j * 3 + c], s);
        o[c] = s;
    }
    out[3 * i + 0] = o[0];
    out[3 * i + 1] = o[1];
    out[3 * i + 2] = o[2];
}

extern "C" void kernel_launch(void* const* d_in, const int* in_sizes, int n_in,
                              void* d_out, int out_size, void* d_ws, size_t ws_size,
                              hipStream_t stream) {
    const float* x   = (const float*)d_in[0];
    const int*   ei  = (const int*)d_in[1];   // [2, E] int32
    const float* W1  = (const float*)d_in[5];
    const float* b1  = (const float*)d_in[6];
    const float* W2  = (const float*)d_in[7];
    const float* b2  = (const float*)d_in[8];
    const float* W3  = (const float*)d_in[9];
    const float* b3  = (const float*)d_in[10];

    const int n_nodes = in_sizes[0] / 3;
    const int n_edges = in_sizes[1] / 2;
    const int* rows = ei;            // edge_index[0]
    const int* cols = ei + n_edges;  // edge_index[1]
    float* out = (float*)d_out;

    const int nb = (n_nodes + TILE - 1) >> SH;

    int chunk = (n_edges + NBLK - 1) / NBLK;
    chunk = (chunk + 3) & ~3;        // keep per-block int4 loads 16B-aligned

    // Path A layout: x4[N] f4 | packed[E] | packed3[E] | colStart[nb*4096+1]
    //                | hist[NBLK*nb] | keyTotal[nb] | keyStart[nb+1]
    const size_t off_x4     = 0;
    const size_t off_packed = off_x4 + (size_t)n_nodes * 16;
    const size_t off_pk3    = off_packed + (size_t)n_edges * 4;
    const size_t off_cs     = off_pk3 + (size_t)n_edges * 4;
    const size_t off_hist   = off_cs + ((size_t)nb * TILE + 1) * 4;
    const size_t off_kt     = off_hist + (size_t)NBLK * nb * 4;
    const size_t off_ks     = off_kt + (size_t)nb * 4;
    const size_t needA      = off_ks + (size_t)(nb + 1) * 4;

    const size_t needB = (size_t)n_edges * 4 + (size_t)NBLK * nb * 4
                       + (size_t)nb * 4 + (size_t)(nb + 1) * 4;
    const bool okA = (ws_size >= needA) && (nb <= MAXNB) && (n_nodes <= (1 << 20));
    const bool okB = (ws_size >= needB) && (nb <= MAXNB) && (n_nodes <= (1 << 20));

    if (okA) {
        float4*   x4       = (float4*)((char*)d_ws + off_x4);
        unsigned* packed   = (unsigned*)((char*)d_ws + off_packed);
        unsigned* packed3  = (unsigned*)((char*)d_ws + off_pk3);
        int*      colStart = (int*)((char*)d_ws + off_cs);
        int*      hist     = (int*)((char*)d_ws + off_hist);
        int*      keyTotal = (int*)((char*)d_ws + off_kt);
        int*      keyStart = (int*)((char*)d_ws + off_ks);

        pad_x_kernel<<<2048, 256, 0, stream>>>(x, x4, n_nodes);
        hist_kernel<<<NBLK, THR, 0, stream>>>(cols, hist, nb, chunk, n_edges);
        scan_blocks_kernel<<<nb, NBLK, 0, stream>>>(hist, keyTotal, nb);
        scan_keys_kernel<<<1, 1024, 0, stream>>>(keyTotal, keyStart, nb);
        scatter_kernel<<<NBLK, THR, 0, stream>>>(cols, rows, hist, keyStart,
                                                 packed, nb, chunk, n_edges);
        reorder_col_kernel<<<nb, THR, 0, stream>>>(packed, packed3, keyStart,
                                                   colStart, nb, n_edges);
        agg_csc_mlp_kernel<<<(n_nodes + 255) / 256, 256, 0, stream>>>(
            packed3, x4, x, colStart, W1, b1, W2, b2, W3, b3, out, n_nodes);
    } else if (okB) {
        unsigned* packed = (unsigned*)d_ws;
        int* hist        = (int*)(packed + n_edges);
        int* keyTotal    = hist + (size_t)NBLK * nb;
        int* keyStart    = keyTotal + nb;

        hist_kernel<<<NBLK, THR, 0, stream>>>(cols, hist, nb, chunk, n_edges);
        scan_blocks_kernel<<<nb, NBLK, 0, stream>>>(hist, keyTotal, nb);
        scan_keys_kernel<<<1, 1024, 0, stream>>>(keyTotal, keyStart, nb);
        scatter_kernel<<<NBLK, THR, 0, stream>>>(cols, rows, hist, keyStart,
                                                 packed, nb, chunk, n_edges);
        bucket_agg_mlp_kernel<<<nb, THR, 0, stream>>>(
            packed, x, keyStart, W1, b1, W2, b2, W3, b3, out, n_nodes);
    } else {
        hipMemsetAsync(d_out, 0, (size_t)out_size * sizeof(float), stream);
        edge_scatter_kernel<<<8192, 256, 0, stream>>>(rows, cols, x, out, n_edges);
        node_mlp_kernel<<<(n_nodes + 255) / 256, 256, 0, stream>>>(
            x, W1, b1, W2, b2, W3, b3, out, n_nodes);
    }
}

// Round 12
// 825.406 us; speedup vs baseline: 1.3267x; 1.3267x over previous
//
#include <hip/hip_runtime.h>

// NodeModel: agg = segment_sum(x[row], col); h = concat(x, agg); out = MLP(h).
//
// Path A (= round-10 structure + 8-deep ILP in the agg):
//   0) pad x -> x4 (float4/node).
//   1) counting-sort by col-bucket (col>>12, 245 cursors); payload
//      (row<<12)|col_local.
//   2) reorder: per col-bucket, 256-bin counting sort by row>>12 -> packed2;
//      emits 8 row-window (row>>17) sub-segment offsets.
//   3) agg_win: grid = 8 windows x 245 buckets (w-major), window-confined
//      gathers (L2-resident, proven: FETCH 1.28GB->162MB in r10). NEW: 8-deep
//      batched loads -> 2x+ outstanding misses per CU (r10 was latency/ILP-
//      bound at 4-deep: 427us with only 162MB of traffic).
//   4) merge 8 partials + fused node MLP.
// Path B (smaller ws): col-sort + LDS-atomic agg (round-3, 728us).
// Path C: global atomicAdd + separate MLP.

#define SH    12
#define TILE  4096
#define MAXNB 256
#define NBLK  512
#define THR   1024
#define NWIN  8

// ---------------- sort kernels ----------------

__global__ __launch_bounds__(THR) void hist_kernel(
    const int* __restrict__ key, int* __restrict__ hist,
    int nb, int chunk, int n_edges)
{
    __shared__ int lh[MAXNB];
    const int t = threadIdx.x, b = blockIdx.x;
    for (int k = t; k < nb; k += THR) lh[k] = 0;
    __syncthreads();

    long long s = (long long)b * chunk;
    long long e = s + chunk; if (e > n_edges) e = n_edges;
    if (s < e) {
        const int n = (int)(e - s);
        const int n4 = n >> 2;
        const int4* __restrict__ k4p = reinterpret_cast<const int4*>(key + s);
        for (int i = t; i < n4; i += THR) {
            int4 c = k4p[i];
            atomicAdd(&lh[(unsigned)c.x >> SH], 1);
            atomicAdd(&lh[(unsigned)c.y >> SH], 1);
            atomicAdd(&lh[(unsigned)c.z >> SH], 1);
            atomicAdd(&lh[(unsigned)c.w >> SH], 1);
        }
        for (int i = (n4 << 2) + t; i < n; i += THR)
            atomicAdd(&lh[(unsigned)key[s + i] >> SH], 1);
    }
    __syncthreads();
    for (int k = t; k < nb; k += THR) hist[(size_t)b * nb + k] = lh[k];
}

__global__ __launch_bounds__(NBLK) void scan_blocks_kernel(
    int* __restrict__ hist, int* __restrict__ keyTotal, int nb)
{
    __shared__ int sd[NBLK];
    const int t = threadIdx.x, k = blockIdx.x;
    const int v = hist[(size_t)t * nb + k];
    sd[t] = v; __syncthreads();
#pragma unroll
    for (int off = 1; off < NBLK; off <<= 1) {
        int a = (t >= off) ? sd[t - off] : 0;
        __syncthreads();
        sd[t] += a;
        __syncthreads();
    }
    hist[(size_t)t * nb + k] = sd[t] - v;
    if (t == NBLK - 1) keyTotal[k] = sd[t];
}

__global__ __launch_bounds__(1024) void scan_keys_kernel(
    const int* __restrict__ keyTotal, int* __restrict__ keyStart, int nb)
{
    __shared__ int sd[1024];
    const int t = threadIdx.x;
    const int v = (t < nb) ? keyTotal[t] : 0;
    sd[t] = v; __syncthreads();
#pragma unroll
    for (int off = 1; off < 1024; off <<= 1) {
        int a = (t >= off) ? sd[t - off] : 0;
        __syncthreads();
        sd[t] += a;
        __syncthreads();
    }
    if (t < nb) keyStart[t] = sd[t] - v;
    if (t == 0) keyStart[nb] = sd[1023];
}

__global__ __launch_bounds__(THR) void scatter_kernel(
    const int* __restrict__ key, const int* __restrict__ other,
    const int* __restrict__ hist, const int* __restrict__ keyStart,
    unsigned* __restrict__ packed, int nb, int chunk, int n_edges)
{
    __shared__ int lc[MAXNB];
    const int t = threadIdx.x, b = blockIdx.x;
    for (int k = t; k < nb; k += THR)
        lc[k] = keyStart[k] + hist[(size_t)b * nb + k];
    __syncthreads();

    long long s = (long long)b * chunk;
    long long e = s + chunk; if (e > n_edges) e = n_edges;
    if (s < e) {
        const int n = (int)(e - s);
        const int n4 = n >> 2;
        const int4* __restrict__ k4p = reinterpret_cast<const int4*>(key + s);
        const int4* __restrict__ o4p = reinterpret_cast<const int4*>(other + s);
        for (int i = t; i < n4; i += THR) {
            int4 c = k4p[i];
            int4 r = o4p[i];
            int p;
            p = atomicAdd(&lc[(unsigned)c.x >> SH], 1);
            packed[p] = ((unsigned)r.x << SH) | ((unsigned)c.x & (TILE - 1));
            p = atomicAdd(&lc[(unsigned)c.y >> SH], 1);
            packed[p] = ((unsigned)r.y << SH) | ((unsigned)c.y & (TILE - 1));
            p = atomicAdd(&lc[(unsigned)c.z >> SH], 1);
            packed[p] = ((unsigned)r.z << SH) | ((unsigned)c.z & (TILE - 1));
            p = atomicAdd(&lc[(unsigned)c.w >> SH], 1);
            packed[p] = ((unsigned)r.w << SH) | ((unsigned)c.w & (TILE - 1));
        }
        for (int i = (n4 << 2) + t; i < n; i += THR) {
            int c = key[s + i], r = other[s + i];
            int p = atomicAdd(&lc[(unsigned)c >> SH], 1);
            packed[p] = ((unsigned)r << SH) | ((unsigned)c & (TILE - 1));
        }
    }
}

// ---------------- x padding ----------------

__global__ __launch_bounds__(256) void pad_x_kernel(
    const float* __restrict__ x, float4* __restrict__ x4, int n)
{
    const int stride = gridDim.x * 256;
    for (int i = blockIdx.x * 256 + threadIdx.x; i < n; i += stride) {
        float4 v;
        v.x = x[3 * i + 0];
        v.y = x[3 * i + 1];
        v.z = x[3 * i + 2];
        v.w = 0.0f;
        x4[i] = v;
    }
}

// ------- per-bucket row reorder (256-bin counting sort) + window offsets ----

__global__ __launch_bounds__(THR) void reorder_kernel(
    const unsigned* __restrict__ packed, unsigned* __restrict__ packed2,
    const int* __restrict__ keyStart, int* __restrict__ subStart)
{
    __shared__ int h[256];
    __shared__ int sd[256];
    __shared__ int cur[256];
    const int t = threadIdx.x, cb = blockIdx.x;
    if (t < 256) h[t] = 0;
    __syncthreads();

    const int s = keyStart[cb], e = keyStart[cb + 1];

    for (int i = s + t; i < e; i += THR)
        atomicAdd(&h[packed[i] >> 24], 1);
    __syncthreads();

    if (t < 256) sd[t] = h[t];
    __syncthreads();
#pragma unroll
    for (int off = 1; off < 256; off <<= 1) {
        int a = 0;
        if (t < 256 && t >= off) a = sd[t - off];
        __syncthreads();
        if (t < 256) sd[t] += a;
        __syncthreads();
    }
    if (t < 256) cur[t] = s + sd[t] - h[t];
    __syncthreads();

    if (t < NWIN) subStart[cb * (NWIN + 1) + t] = cur[t * 32];
    if (t == 0)   subStart[cb * (NWIN + 1) + NWIN] = e;
    __syncthreads();

    for (int i = s + t; i < e; i += THR) {
        unsigned p = packed[i];
        int q = atomicAdd(&cur[p >> 24], 1);
        packed2[q] = p;
    }
}

// ---------------- window-split agg, 8-deep ILP ----------------

__global__ __launch_bounds__(THR) void agg_win_kernel(
    const unsigned* __restrict__ packed2, const float4* __restrict__ x4,
    const int* __restrict__ subStart, float* __restrict__ partial,
    int n_nodes, int nb)
{
    __shared__ float acc[TILE * 3];   // 48 KB
    const int t = threadIdx.x;
    const int cb = blockIdx.x % nb;       // bucket
    const int w  = blockIdx.x / nb;       // row window (w-major dispatch)
    for (int f = t; f < TILE * 3; f += THR) acc[f] = 0.0f;
    __syncthreads();

    const int s = subStart[cb * (NWIN + 1) + w];
    const int e = subStart[cb * (NWIN + 1) + w + 1];

    int i = s + t;
    // 8-deep: issue 8 packed loads, then 8 independent gathers, then atomics.
    for (; i + 7 * THR < e; i += 8 * THR) {
        unsigned p[8];
#pragma unroll
        for (int u = 0; u < 8; ++u) p[u] = packed2[i + u * THR];
        float4 v[8];
#pragma unroll
        for (int u = 0; u < 8; ++u) v[u] = x4[p[u] >> SH];
#pragma unroll
        for (int u = 0; u < 8; ++u) {
            const int j = (int)(p[u] & (TILE - 1)) * 3;
            atomicAdd(&acc[j + 0], v[u].x);
            atomicAdd(&acc[j + 1], v[u].y);
            atomicAdd(&acc[j + 2], v[u].z);
        }
    }
    for (; i + 3 * THR < e; i += 4 * THR) {
        unsigned p[4];
#pragma unroll
        for (int u = 0; u < 4; ++u) p[u] = packed2[i + u * THR];
        float4 v[4];
#pragma unroll
        for (int u = 0; u < 4; ++u) v[u] = x4[p[u] >> SH];
#pragma unroll
        for (int u = 0; u < 4; ++u) {
            const int j = (int)(p[u] & (TILE - 1)) * 3;
            atomicAdd(&acc[j + 0], v[u].x);
            atomicAdd(&acc[j + 1], v[u].y);
            atomicAdd(&acc[j + 2], v[u].z);
        }
    }
    for (; i < e; i += THR) {
        unsigned p = packed2[i];
        float4 v = x4[p >> SH];
        const int j = (int)(p & (TILE - 1)) * 3;
        atomicAdd(&acc[j + 0], v.x);
        atomicAdd(&acc[j + 1], v.y);
        atomicAdd(&acc[j + 2], v.z);
    }
    __syncthreads();

    const long long base = (long long)cb << SH;
    long long lim = (long long)n_nodes - base;
    if (lim > TILE) lim = TILE;
    if (lim <= 0) return;
    float* __restrict__ dst = partial + ((size_t)w * n_nodes + base) * 3;
    const int fl = (int)lim * 3;
    for (int f = t; f < fl; f += THR) dst[f] = acc[f];
}

// ---------------- merge NWIN partials + fused MLP ----------------

__global__ __launch_bounds__(256) void merge_mlp_kernel(
    const float* __restrict__ partial, const float* __restrict__ x,
    const float* __restrict__ W1, const float* __restrict__ b1,
    const float* __restrict__ W2, const float* __restrict__ b2,
    const float* __restrict__ W3, const float* __restrict__ b3,
    float* __restrict__ out, int n_nodes)
{
    __shared__ float sW1[96], sb1[16], sW2[256], sb2[16], sW3[48], sb3[3];
    const int t = threadIdx.x;
    if (t < 96)  sW1[t] = W1[t];
    if (t < 16)  sb1[t] = b1[t];
    sW2[t] = W2[t];
    if (t < 16)  sb2[t] = b2[t];
    if (t < 48)  sW3[t] = W3[t];
    if (t < 3)   sb3[t] = b3[t];
    __syncthreads();

    const int i = blockIdx.x * 256 + t;
    if (i >= n_nodes) return;

    float a0 = 0.0f, a1 = 0.0f, a2 = 0.0f;
#pragma unroll
    for (int w = 0; w < NWIN; ++w) {
        const float* __restrict__ p = partial + ((size_t)w * n_nodes + i) * 3;
        a0 += p[0]; a1 += p[1]; a2 += p[2];
    }

    float in6[6];
    in6[0] = x[3 * i + 0];
    in6[1] = x[3 * i + 1];
    in6[2] = x[3 * i + 2];
    in6[3] = a0;
    in6[4] = a1;
    in6[5] = a2;

    float h1[16];
#pragma unroll
    for (int j = 0; j < 16; ++j) {
        float s = sb1[j];
#pragma unroll
        for (int k = 0; k < 6; ++k) s = fmaf(in6[k], sW1[k * 16 + j], s);
        h1[j] = fmaxf(s, 0.0f);
    }
    float h2[16];
#pragma unroll
    for (int j = 0; j < 16; ++j) {
        float s = sb2[j];
#pragma unroll
        for (int k = 0; k < 16; ++k) s = fmaf(h1[k], sW2[k * 16 + j], s);
        h2[j] = fmaxf(s, 0.0f);
    }
    float o0 = sb3[0], o1 = sb3[1], o2 = sb3[2];
#pragma unroll
    for (int j = 0; j < 16; ++j) {
        o0 = fmaf(h2[j], sW3[j * 3 + 0], o0);
        o1 = fmaf(h2[j], sW3[j * 3 + 1], o1);
        o2 = fmaf(h2[j], sW3[j * 3 + 2], o2);
    }
    out[3 * i + 0] = o0;
    out[3 * i + 1] = o1;
    out[3 * i + 2] = o2;
}

// ---------------- Path B: direct gather agg + fused MLP ----------------

__global__ __launch_bounds__(THR) void bucket_agg_mlp_kernel(
    const unsigned* __restrict__ packed, const float* __restrict__ x,
    const int* __restrict__ keyStart,
    const float* __restrict__ W1, const float* __restrict__ b1,
    const float* __restrict__ W2, const float* __restrict__ b2,
    const float* __restrict__ W3, const float* __restrict__ b3,
    float* __restrict__ out, int n_nodes)
{
    __shared__ float acc[TILE * 3];
    __shared__ float sW1[96], sb1[16], sW2[256], sb2[16], sW3[48], sb3[3];
    const int t = threadIdx.x, k = blockIdx.x;

    if (t < 96)  sW1[t] = W1[t];
    if (t < 16)  sb1[t] = b1[t];
    if (t < 256) sW2[t] = W2[t];
    if (t >= 256 && t < 272) sb2[t - 256] = b2[t - 256];
    if (t >= 272 && t < 320) sW3[t - 272] = W3[t - 272];
    if (t >= 320 && t < 323) sb3[t - 320] = b3[t - 320];
    for (int f = t; f < TILE * 3; f += THR) acc[f] = 0.0f;
    __syncthreads();

    const int s = keyStart[k];
    const int e = keyStart[k + 1];
    for (int i = s + t; i < e; i += THR) {
        const unsigned p = packed[i];
        const float* __restrict__ xs = x + 3ll * (p >> SH);
        const int j = (int)(p & (TILE - 1)) * 3;
        atomicAdd(&acc[j + 0], xs[0]);
        atomicAdd(&acc[j + 1], xs[1]);
        atomicAdd(&acc[j + 2], xs[2]);
    }
    __syncthreads();

    const long long base = (long long)k << SH;
    long long lim = (long long)n_nodes - base;
    if (lim > TILE) lim = TILE;
    if (lim <= 0) return;

    for (int j = t; j < (int)lim; j += THR) {
        const long long node = base + j;
        float in6[6];
        in6[0] = x[3 * node + 0];
        in6[1] = x[3 * node + 1];
        in6[2] = x[3 * node + 2];
        in6[3] = acc[3 * j + 0];
        in6[4] = acc[3 * j + 1];
        in6[5] = acc[3 * j + 2];

        float h1[16];
#pragma unroll
        for (int q = 0; q < 16; ++q) {
            float sv = sb1[q];
#pragma unroll
            for (int r = 0; r < 6; ++r) sv = fmaf(in6[r], sW1[r * 16 + q], sv);
            h1[q] = fmaxf(sv, 0.0f);
        }
        float h2[16];
#pragma unroll
        for (int q = 0; q < 16; ++q) {
            float sv = sb2[q];
#pragma unroll
            for (int r = 0; r < 16; ++r) sv = fmaf(h1[r], sW2[r * 16 + q], sv);
            h2[q] = fmaxf(sv, 0.0f);
        }
        float o0 = sb3[0], o1 = sb3[1], o2 = sb3[2];
#pragma unroll
        for (int q = 0; q < 16; ++q) {
            o0 = fmaf(h2[q], sW3[q * 3 + 0], o0);
            o1 = fmaf(h2[q], sW3[q * 3 + 1], o1);
            o2 = fmaf(h2[q], sW3[q * 3 + 2], o2);
        }
        out[3 * node + 0] = o0;
        out[3 * node + 1] = o1;
        out[3 * node + 2] = o2;
    }
}

// ---------------- Path C ----------------

__global__ __launch_bounds__(256) void edge_scatter_kernel(
    const int* __restrict__ rows, const int* __restrict__ cols,
    const float* __restrict__ x, float* __restrict__ agg, int n_edges)
{
    const long long tid = (long long)blockIdx.x * blockDim.x + threadIdx.x;
    const long long stride = (long long)gridDim.x * blockDim.x;
    for (long long i = tid; i < n_edges; i += stride) {
        int r = rows[i], c = cols[i];
        const float* xs = x + 3ll * r; float* a = agg + 3ll * c;
        atomicAdd(a + 0, xs[0]); atomicAdd(a + 1, xs[1]); atomicAdd(a + 2, xs[2]);
    }
}

__global__ __launch_bounds__(256) void node_mlp_kernel(
    const float* __restrict__ x,
    const float* __restrict__ W1, const float* __restrict__ b1,
    const float* __restrict__ W2, const float* __restrict__ b2,
    const float* __restrict__ W3, const float* __restrict__ b3,
    float* __restrict__ out, int n_nodes)
{
    __shared__ float sW1[96], sb1[16], sW2[256], sb2[16], sW3[48], sb3[3];
    const int t = threadIdx.x;
    if (t < 96)  sW1[t] = W1[t];
    if (t < 16)  sb1[t] = b1[t];
    sW2[t] = W2[t];
    if (t < 16)  sb2[t] = b2[t];
    if (t < 48)  sW3[t] = W3[t];
    if (t < 3)   sb3[t] = b3[t];
    __syncthreads();

    const int i = blockIdx.x * 256 + t;
    if (i >= n_nodes) return;

    float in6[6];
    in6[0] = x[3 * i + 0];
    in6[1] = x[3 * i + 1];
    in6[2] = x[3 * i + 2];
    in6[3] = out[3 * i + 0];
    in6[4] = out[3 * i + 1];
    in6[5] = out[3 * i + 2];

    float h1[16];
#pragma unroll
    for (int j = 0; j < 16; ++j) {
        float s = sb1[j];
#pragma unroll
        for (int k = 0; k < 6; ++k) s = fmaf(in6[k], sW1[k * 16 + j], s);
        h1[j] = fmaxf(s, 0.0f);
    }
    float h2[16];
#pragma unroll
    for (int j = 0; j < 16; ++j) {
        float s = sb2[j];
#pragma unroll
        for (int k = 0; k < 16; ++k) s = fmaf(h1[k], sW2[k * 16 + j], s);
        h2[j] = fmaxf(s, 0.0f);
    }
    float o[3];
#pragma unroll
    for (int c = 0; c < 3; ++c) {
        float s = sb3[c];
#pragma unroll
        for (int j = 0; j < 16; ++j) s = fmaf(h2[j], sW3[j * 3 + c], s);
        o[c] = s;
    }
    out[3 * i + 0] = o[0];
    out[3 * i + 1] = o[1];
    out[3 * i + 2] = o[2];
}

extern "C" void kernel_launch(void* const* d_in, const int* in_sizes, int n_in,
                              void* d_out, int out_size, void* d_ws, size_t ws_size,
                              hipStream_t stream) {
    const float* x   = (const float*)d_in[0];
    const int*   ei  = (const int*)d_in[1];   // [2, E] int32
    const float* W1  = (const float*)d_in[5];
    const float* b1  = (const float*)d_in[6];
    const float* W2  = (const float*)d_in[7];
    const float* b2  = (const float*)d_in[8];
    const float* W3  = (const float*)d_in[9];
    const float* b3  = (const float*)d_in[10];

    const int n_nodes = in_sizes[0] / 3;
    const int n_edges = in_sizes[1] / 2;
    const int* rows = ei;            // edge_index[0]
    const int* cols = ei + n_edges;  // edge_index[1]
    float* out = (float*)d_out;

    const int nb = (n_nodes + TILE - 1) >> SH;

    int chunk = (n_edges + NBLK - 1) / NBLK;
    chunk = (chunk + 3) & ~3;        // keep per-block int4 loads 16B-aligned

    // Path A layout: x4[N] f4 | packed[E] | packed2[E] | partial[NWIN*N*3]
    //                | hist[NBLK*nb] | keyTotal[nb] | keyStart[nb+1]
    //                | subStart[nb*(NWIN+1)]
    const size_t off_x4     = 0;
    const size_t off_packed = off_x4 + (size_t)n_nodes * 16;
    const size_t off_pk2    = off_packed + (size_t)n_edges * 4;
    const size_t off_part   = off_pk2 + (size_t)n_edges * 4;
    const size_t off_hist   = off_part + (size_t)NWIN * n_nodes * 12;
    const size_t off_kt     = off_hist + (size_t)NBLK * nb * 4;
    const size_t off_ks     = off_kt + (size_t)nb * 4;
    const size_t off_ss     = off_ks + (size_t)(nb + 1) * 4;
    const size_t needA      = off_ss + (size_t)nb * (NWIN + 1) * 4;

    const size_t needB = (size_t)n_edges * 4 + (size_t)NBLK * nb * 4
                       + (size_t)nb * 4 + (size_t)(nb + 1) * 4;
    const bool okA = (ws_size >= needA) && (nb <= MAXNB) && (n_nodes <= (1 << 20));
    const bool okB = (ws_size >= needB) && (nb <= MAXNB) && (n_nodes <= (1 << 20));

    if (okA) {
        float4*   x4       = (float4*)((char*)d_ws + off_x4);
        unsigned* packed   = (unsigned*)((char*)d_ws + off_packed);
        unsigned* packed2  = (unsigned*)((char*)d_ws + off_pk2);
        float*    partial  = (float*)((char*)d_ws + off_part);
        int*      hist     = (int*)((char*)d_ws + off_hist);
        int*      keyTotal = (int*)((char*)d_ws + off_kt);
        int*      keyStart = (int*)((char*)d_ws + off_ks);
        int*      subStart = (int*)((char*)d_ws + off_ss);

        pad_x_kernel<<<2048, 256, 0, stream>>>(x, x4, n_nodes);
        hist_kernel<<<NBLK, THR, 0, stream>>>(cols, hist, nb, chunk, n_edges);
        scan_blocks_kernel<<<nb, NBLK, 0, stream>>>(hist, keyTotal, nb);
        scan_keys_kernel<<<1, 1024, 0, stream>>>(keyTotal, keyStart, nb);
        scatter_kernel<<<NBLK, THR, 0, stream>>>(cols, rows, hist, keyStart,
                                                 packed, nb, chunk, n_edges);
        reorder_kernel<<<nb, THR, 0, stream>>>(packed, packed2, keyStart, subStart);
        agg_win_kernel<<<nb * NWIN, THR, 0, stream>>>(packed2, x4, subStart,
                                                      partial, n_nodes, nb);
        merge_mlp_kernel<<<(n_nodes + 255) / 256, 256, 0, stream>>>(
            partial, x, W1, b1, W2, b2, W3, b3, out, n_nodes);
    } else if (okB) {
        unsigned* packed = (unsigned*)d_ws;
        int* hist        = (int*)(packed + n_edges);
        int* keyTotal    = hist + (size_t)NBLK * nb;
        int* keyStart    = keyTotal + nb;

        hist_kernel<<<NBLK, THR, 0, stream>>>(cols, hist, nb, chunk, n_edges);
        scan_blocks_kernel<<<nb, NBLK, 0, stream>>>(hist, keyTotal, nb);
        scan_keys_kernel<<<1, 1024, 0, stream>>>(keyTotal, keyStart, nb);
        scatter_kernel<<<NBLK, THR, 0, stream>>>(cols, rows, hist, keyStart,
                                                 packed, nb, chunk, n_edges);
        bucket_agg_mlp_kernel<<<nb, THR, 0, stream>>>(
            packed, x, keyStart, W1, b1, W2, b2, W3, b3, out, n_nodes);
    } else {
        hipMemsetAsync(d_out, 0, (size_t)out_size * sizeof(float), stream);
        edge_scatter_kernel<<<8192, 256, 0, stream>>>(rows, cols, x, out, n_edges);
        node_mlp_kernel<<<(n_nodes + 255) / 256, 256, 0, stream>>>(
            x, W1, b1, W2, b2, W3, b3, out, n_nodes);
    }
}

// Round 13
// 668.152 us; speedup vs baseline: 1.6390x; 1.2354x over previous
//
#include <hip/hip_runtime.h>

// NodeModel: agg = segment_sum(x[row], col); h = concat(x, agg); out = MLP(h).
//
// Pipeline (fast path) — best measured config (round 7, 669us):
//   0) pad x -> x4 (float4/node): gathers become single aligned 16B loads.
//   1) counting-sort edges by col-bucket (col>>12, 245 keys, the proven
//      write-combining-safe cursor count); payload (row<<12)|col_local.
//   2) split-K agg: each bucket's segment is processed by SPLITK blocks
//      (grid ~980 -> high occupancy), each accumulating into a private 48KB
//      LDS tile and writing a partial tile to ws. Runs at the measured
//      ~10cyc/edge/CU per-edge request floor (437us) — invariant across
//      traffic (0.16-2GB), occupancy (42-86%), ILP (2-8 deep), and
//      atomic-free variants (rounds 8-12).
//   3) merge SPLITK partials + fused node MLP -> out.
// Fallback B (smaller ws): round-3 single-block-per-bucket agg (728us).
// Fallback C: global atomicAdd + separate MLP.

#define SH     12
#define TILE   4096           // nodes per col-bucket (48 KB LDS acc)
#define MAXNB  256
#define NBLK   512            // edge chunks for hist/scatter
#define THR    1024
#define SPLITK 4

// ---------------- sort kernels ----------------

__global__ __launch_bounds__(THR) void hist_kernel(
    const int* __restrict__ key, int* __restrict__ hist,
    int nb, int chunk, int n_edges)
{
    __shared__ int lh[MAXNB];
    const int t = threadIdx.x, b = blockIdx.x;
    for (int k = t; k < nb; k += THR) lh[k] = 0;
    __syncthreads();

    long long s = (long long)b * chunk;
    long long e = s + chunk; if (e > n_edges) e = n_edges;
    if (s < e) {
        const int n = (int)(e - s);
        const int n4 = n >> 2;
        const int4* __restrict__ k4p = reinterpret_cast<const int4*>(key + s);
        for (int i = t; i < n4; i += THR) {
            int4 c = k4p[i];
            atomicAdd(&lh[(unsigned)c.x >> SH], 1);
            atomicAdd(&lh[(unsigned)c.y >> SH], 1);
            atomicAdd(&lh[(unsigned)c.z >> SH], 1);
            atomicAdd(&lh[(unsigned)c.w >> SH], 1);
        }
        for (int i = (n4 << 2) + t; i < n; i += THR)
            atomicAdd(&lh[(unsigned)key[s + i] >> SH], 1);
    }
    __syncthreads();
    for (int k = t; k < nb; k += THR) hist[(size_t)b * nb + k] = lh[k];
}

__global__ __launch_bounds__(NBLK) void scan_blocks_kernel(
    int* __restrict__ hist, int* __restrict__ keyTotal, int nb)
{
    __shared__ int sd[NBLK];
    const int t = threadIdx.x, k = blockIdx.x;
    const int v = hist[(size_t)t * nb + k];
    sd[t] = v; __syncthreads();
#pragma unroll
    for (int off = 1; off < NBLK; off <<= 1) {
        int a = (t >= off) ? sd[t - off] : 0;
        __syncthreads();
        sd[t] += a;
        __syncthreads();
    }
    hist[(size_t)t * nb + k] = sd[t] - v;
    if (t == NBLK - 1) keyTotal[k] = sd[t];
}

__global__ __launch_bounds__(1024) void scan_keys_kernel(
    const int* __restrict__ keyTotal, int* __restrict__ keyStart, int nb)
{
    __shared__ int sd[1024];
    const int t = threadIdx.x;
    const int v = (t < nb) ? keyTotal[t] : 0;
    sd[t] = v; __syncthreads();
#pragma unroll
    for (int off = 1; off < 1024; off <<= 1) {
        int a = (t >= off) ? sd[t - off] : 0;
        __syncthreads();
        sd[t] += a;
        __syncthreads();
    }
    if (t < nb) keyStart[t] = sd[t] - v;
    if (t == 0) keyStart[nb] = sd[1023];
}

__global__ __launch_bounds__(THR) void scatter_kernel(
    const int* __restrict__ key, const int* __restrict__ other,
    const int* __restrict__ hist, const int* __restrict__ keyStart,
    unsigned* __restrict__ packed, int nb, int chunk, int n_edges)
{
    __shared__ int lc[MAXNB];
    const int t = threadIdx.x, b = blockIdx.x;
    for (int k = t; k < nb; k += THR)
        lc[k] = keyStart[k] + hist[(size_t)b * nb + k];
    __syncthreads();

    long long s = (long long)b * chunk;
    long long e = s + chunk; if (e > n_edges) e = n_edges;
    if (s < e) {
        const int n = (int)(e - s);
        const int n4 = n >> 2;
        const int4* __restrict__ k4p = reinterpret_cast<const int4*>(key + s);
        const int4* __restrict__ o4p = reinterpret_cast<const int4*>(other + s);
        for (int i = t; i < n4; i += THR) {
            int4 c = k4p[i];
            int4 r = o4p[i];
            int p;
            p = atomicAdd(&lc[(unsigned)c.x >> SH], 1);
            packed[p] = ((unsigned)r.x << SH) | ((unsigned)c.x & (TILE - 1));
            p = atomicAdd(&lc[(unsigned)c.y >> SH], 1);
            packed[p] = ((unsigned)r.y << SH) | ((unsigned)c.y & (TILE - 1));
            p = atomicAdd(&lc[(unsigned)c.z >> SH], 1);
            packed[p] = ((unsigned)r.z << SH) | ((unsigned)c.z & (TILE - 1));
            p = atomicAdd(&lc[(unsigned)c.w >> SH], 1);
            packed[p] = ((unsigned)r.w << SH) | ((unsigned)c.w & (TILE - 1));
        }
        for (int i = (n4 << 2) + t; i < n; i += THR) {
            int c = key[s + i], r = other[s + i];
            int p = atomicAdd(&lc[(unsigned)c >> SH], 1);
            packed[p] = ((unsigned)r << SH) | ((unsigned)c & (TILE - 1));
        }
    }
}

// ---------------- x padding ----------------

__global__ __launch_bounds__(256) void pad_x_kernel(
    const float* __restrict__ x, float4* __restrict__ x4, int n)
{
    const int stride = gridDim.x * 256;
    for (int i = blockIdx.x * 256 + threadIdx.x; i < n; i += stride) {
        float4 v;
        v.x = x[3 * i + 0];
        v.y = x[3 * i + 1];
        v.z = x[3 * i + 2];
        v.w = 0.0f;
        x4[i] = v;
    }
}

// ---------------- split-K agg ----------------

__global__ __launch_bounds__(THR) void agg_partial_kernel(
    const unsigned* __restrict__ packed, const float4* __restrict__ x4,
    const int* __restrict__ keyStart, float* __restrict__ partial,
    int n_nodes, int nb)
{
    __shared__ float acc[TILE * 3];   // 48 KB
    const int t = threadIdx.x;
    const int k  = blockIdx.x % nb;     // bucket
    const int sl = blockIdx.x / nb;     // slice 0..SPLITK-1
    for (int f = t; f < TILE * 3; f += THR) acc[f] = 0.0f;
    __syncthreads();

    const int s0 = keyStart[k], e0 = keyStart[k + 1];
    const long long len = e0 - s0;
    const int s = s0 + (int)(len * sl / SPLITK);
    const int e = s0 + (int)(len * (sl + 1) / SPLITK);

    int i = s + t;
    for (; i + 3 * THR < e; i += 4 * THR) {
        unsigned p0 = packed[i];
        unsigned p1 = packed[i + THR];
        unsigned p2 = packed[i + 2 * THR];
        unsigned p3 = packed[i + 3 * THR];
        float4 v0 = x4[p0 >> SH];
        float4 v1 = x4[p1 >> SH];
        float4 v2 = x4[p2 >> SH];
        float4 v3 = x4[p3 >> SH];
        int j0 = (int)(p0 & (TILE - 1)) * 3;
        int j1 = (int)(p1 & (TILE - 1)) * 3;
        int j2 = (int)(p2 & (TILE - 1)) * 3;
        int j3 = (int)(p3 & (TILE - 1)) * 3;
        atomicAdd(&acc[j0 + 0], v0.x); atomicAdd(&acc[j0 + 1], v0.y); atomicAdd(&acc[j0 + 2], v0.z);
        atomicAdd(&acc[j1 + 0], v1.x); atomicAdd(&acc[j1 + 1], v1.y); atomicAdd(&acc[j1 + 2], v1.z);
        atomicAdd(&acc[j2 + 0], v2.x); atomicAdd(&acc[j2 + 1], v2.y); atomicAdd(&acc[j2 + 2], v2.z);
        atomicAdd(&acc[j3 + 0], v3.x); atomicAdd(&acc[j3 + 1], v3.y); atomicAdd(&acc[j3 + 2], v3.z);
    }
    for (; i < e; i += THR) {
        unsigned p = packed[i];
        float4 v = x4[p >> SH];
        int j = (int)(p & (TILE - 1)) * 3;
        atomicAdd(&acc[j + 0], v.x);
        atomicAdd(&acc[j + 1], v.y);
        atomicAdd(&acc[j + 2], v.z);
    }
    __syncthreads();

    const long long base = (long long)k << SH;
    long long lim = (long long)n_nodes - base;
    if (lim > TILE) lim = TILE;
    if (lim <= 0) return;
    float* __restrict__ dst = partial + ((size_t)sl * n_nodes + base) * 3;
    const int fl = (int)lim * 3;
    for (int f = t; f < fl; f += THR) dst[f] = acc[f];
}

// ---------------- merge + fused MLP ----------------

__global__ __launch_bounds__(256) void merge_mlp_kernel(
    const float* __restrict__ partial, const float* __restrict__ x,
    const float* __restrict__ W1, const float* __restrict__ b1,
    const float* __restrict__ W2, const float* __restrict__ b2,
    const float* __restrict__ W3, const float* __restrict__ b3,
    float* __restrict__ out, int n_nodes)
{
    __shared__ float sW1[96], sb1[16], sW2[256], sb2[16], sW3[48], sb3[3];
    const int t = threadIdx.x;
    if (t < 96)  sW1[t] = W1[t];
    if (t < 16)  sb1[t] = b1[t];
    sW2[t] = W2[t];
    if (t < 16)  sb2[t] = b2[t];
    if (t < 48)  sW3[t] = W3[t];
    if (t < 3)   sb3[t] = b3[t];
    __syncthreads();

    const int i = blockIdx.x * 256 + t;
    if (i >= n_nodes) return;

    float a0 = 0.0f, a1 = 0.0f, a2 = 0.0f;
#pragma unroll
    for (int sl = 0; sl < SPLITK; ++sl) {
        const float* __restrict__ p = partial + ((size_t)sl * n_nodes + i) * 3;
        a0 += p[0]; a1 += p[1]; a2 += p[2];
    }

    float in6[6];
    in6[0] = x[3 * i + 0];
    in6[1] = x[3 * i + 1];
    in6[2] = x[3 * i + 2];
    in6[3] = a0;
    in6[4] = a1;
    in6[5] = a2;

    float h1[16];
#pragma unroll
    for (int j = 0; j < 16; ++j) {
        float s = sb1[j];
#pragma unroll
        for (int k = 0; k < 6; ++k) s = fmaf(in6[k], sW1[k * 16 + j], s);
        h1[j] = fmaxf(s, 0.0f);
    }
    float h2[16];
#pragma unroll
    for (int j = 0; j < 16; ++j) {
        float s = sb2[j];
#pragma unroll
        for (int k = 0; k < 16; ++k) s = fmaf(h1[k], sW2[k * 16 + j], s);
        h2[j] = fmaxf(s, 0.0f);
    }
    float o0 = sb3[0], o1 = sb3[1], o2 = sb3[2];
#pragma unroll
    for (int j = 0; j < 16; ++j) {
        o0 = fmaf(h2[j], sW3[j * 3 + 0], o0);
        o1 = fmaf(h2[j], sW3[j * 3 + 1], o1);
        o2 = fmaf(h2[j], sW3[j * 3 + 2], o2);
    }
    out[3 * i + 0] = o0;
    out[3 * i + 1] = o1;
    out[3 * i + 2] = o2;
}

// ---------------- Fallback B: round-3 agg (one block/bucket, fused MLP) ----

__global__ __launch_bounds__(THR) void bucket_agg_mlp_kernel(
    const unsigned* __restrict__ packed, const float* __restrict__ x,
    const int* __restrict__ keyStart,
    const float* __restrict__ W1, const float* __restrict__ b1,
    const float* __restrict__ W2, const float* __restrict__ b2,
    const float* __restrict__ W3, const float* __restrict__ b3,
    float* __restrict__ out, int n_nodes)
{
    __shared__ float acc[TILE * 3];
    __shared__ float sW1[96], sb1[16], sW2[256], sb2[16], sW3[48], sb3[3];
    const int t = threadIdx.x, k = blockIdx.x;

    if (t < 96)  sW1[t] = W1[t];
    if (t < 16)  sb1[t] = b1[t];
    if (t < 256) sW2[t] = W2[t];
    if (t >= 256 && t < 272) sb2[t - 256] = b2[t - 256];
    if (t >= 272 && t < 320) sW3[t - 272] = W3[t - 272];
    if (t >= 320 && t < 323) sb3[t - 320] = b3[t - 320];
    for (int f = t; f < TILE * 3; f += THR) acc[f] = 0.0f;
    __syncthreads();

    const int s = keyStart[k];
    const int e = keyStart[k + 1];
    int i = s + t;
    for (; i + 3 * THR < e; i += 4 * THR) {
        unsigned p0 = packed[i];
        unsigned p1 = packed[i + THR];
        unsigned p2 = packed[i + 2 * THR];
        unsigned p3 = packed[i + 3 * THR];
        const float* xs0 = x + 3ll * (p0 >> SH);
        const float* xs1 = x + 3ll * (p1 >> SH);
        const float* xs2 = x + 3ll * (p2 >> SH);
        const float* xs3 = x + 3ll * (p3 >> SH);
        float a0 = xs0[0], b0 = xs0[1], c0 = xs0[2];
        float a1 = xs1[0], b1v = xs1[1], c1 = xs1[2];
        float a2 = xs2[0], b2v = xs2[1], c2 = xs2[2];
        float a3 = xs3[0], b3v = xs3[1], c3 = xs3[2];
        int j0 = (int)(p0 & (TILE - 1)) * 3;
        int j1 = (int)(p1 & (TILE - 1)) * 3;
        int j2 = (int)(p2 & (TILE - 1)) * 3;
        int j3 = (int)(p3 & (TILE - 1)) * 3;
        atomicAdd(&acc[j0 + 0], a0); atomicAdd(&acc[j0 + 1], b0);  atomicAdd(&acc[j0 + 2], c0);
        atomicAdd(&acc[j1 + 0], a1); atomicAdd(&acc[j1 + 1], b1v); atomicAdd(&acc[j1 + 2], c1);
        atomicAdd(&acc[j2 + 0], a2); atomicAdd(&acc[j2 + 1], b2v); atomicAdd(&acc[j2 + 2], c2);
        atomicAdd(&acc[j3 + 0], a3); atomicAdd(&acc[j3 + 1], b3v); atomicAdd(&acc[j3 + 2], c3);
    }
    for (; i < e; i += THR) {
        const unsigned p = packed[i];
        const float* __restrict__ xs = x + 3ll * (p >> SH);
        const int j = (int)(p & (TILE - 1)) * 3;
        atomicAdd(&acc[j + 0], xs[0]);
        atomicAdd(&acc[j + 1], xs[1]);
        atomicAdd(&acc[j + 2], xs[2]);
    }
    __syncthreads();

    const long long base = (long long)k << SH;
    long long lim = (long long)n_nodes - base;
    if (lim > TILE) lim = TILE;
    if (lim <= 0) return;

    for (int j = t; j < (int)lim; j += THR) {
        const long long node = base + j;
        float in6[6];
        in6[0] = x[3 * node + 0];
        in6[1] = x[3 * node + 1];
        in6[2] = x[3 * node + 2];
        in6[3] = acc[3 * j + 0];
        in6[4] = acc[3 * j + 1];
        in6[5] = acc[3 * j + 2];

        float h1[16];
#pragma unroll
        for (int q = 0; q < 16; ++q) {
            float sv = sb1[q];
#pragma unroll
            for (int r = 0; r < 6; ++r) sv = fmaf(in6[r], sW1[r * 16 + q], sv);
            h1[q] = fmaxf(sv, 0.0f);
        }
        float h2[16];
#pragma unroll
        for (int q = 0; q < 16; ++q) {
            float sv = sb2[q];
#pragma unroll
            for (int r = 0; r < 16; ++r) sv = fmaf(h1[r], sW2[r * 16 + q], sv);
            h2[q] = fmaxf(sv, 0.0f);
        }
        float o0 = sb3[0], o1 = sb3[1], o2 = sb3[2];
#pragma unroll
        for (int q = 0; q < 16; ++q) {
            o0 = fmaf(h2[q], sW3[q * 3 + 0], o0);
            o1 = fmaf(h2[q], sW3[q * 3 + 1], o1);
            o2 = fmaf(h2[q], sW3[q * 3 + 2], o2);
        }
        out[3 * node + 0] = o0;
        out[3 * node + 1] = o1;
        out[3 * node + 2] = o2;
    }
}

// ---------------- Fallback C ----------------

__global__ __launch_bounds__(256) void edge_scatter_kernel(
    const int* __restrict__ rows, const int* __restrict__ cols,
    const float* __restrict__ x, float* __restrict__ agg, int n_edges)
{
    const long long tid = (long long)blockIdx.x * blockDim.x + threadIdx.x;
    const long long stride = (long long)gridDim.x * blockDim.x;
    for (long long i = tid; i < n_edges; i += stride) {
        int r = rows[i], c = cols[i];
        const float* xs = x + 3ll * r; float* a = agg + 3ll * c;
        atomicAdd(a + 0, xs[0]); atomicAdd(a + 1, xs[1]); atomicAdd(a + 2, xs[2]);
    }
}

__global__ __launch_bounds__(256) void node_mlp_kernel(
    const float* __restrict__ x,
    const float* __restrict__ W1, const float* __restrict__ b1,
    const float* __restrict__ W2, const float* __restrict__ b2,
    const float* __restrict__ W3, const float* __restrict__ b3,
    float* __restrict__ out, int n_nodes)
{
    __shared__ float sW1[96], sb1[16], sW2[256], sb2[16], sW3[48], sb3[3];
    const int t = threadIdx.x;
    if (t < 96)  sW1[t] = W1[t];
    if (t < 16)  sb1[t] = b1[t];
    sW2[t] = W2[t];
    if (t < 16)  sb2[t] = b2[t];
    if (t < 48)  sW3[t] = W3[t];
    if (t < 3)   sb3[t] = b3[t];
    __syncthreads();

    const int i = blockIdx.x * 256 + t;
    if (i >= n_nodes) return;

    float in6[6];
    in6[0] = x[3 * i + 0];
    in6[1] = x[3 * i + 1];
    in6[2] = x[3 * i + 2];
    in6[3] = out[3 * i + 0];
    in6[4] = out[3 * i + 1];
    in6[5] = out[3 * i + 2];

    float h1[16];
#pragma unroll
    for (int j = 0; j < 16; ++j) {
        float s = sb1[j];
#pragma unroll
        for (int k = 0; k < 6; ++k) s = fmaf(in6[k], sW1[k * 16 + j], s);
        h1[j] = fmaxf(s, 0.0f);
    }
    float h2[16];
#pragma unroll
    for (int j = 0; j < 16; ++j) {
        float s = sb2[j];
#pragma unroll
        for (int k = 0; k < 16; ++k) s = fmaf(h1[k], sW2[k * 16 + j], s);
        h2[j] = fmaxf(s, 0.0f);
    }
    float o[3];
#pragma unroll
    for (int c = 0; c < 3; ++c) {
        float s = sb3[c];
#pragma unroll
        for (int j = 0; j < 16; ++j) s = fmaf(h2[j], sW3[j * 3 + c], s);
        o[c] = s;
    }
    out[3 * i + 0] = o[0];
    out[3 * i + 1] = o[1];
    out[3 * i + 2] = o[2];
}

extern "C" void kernel_launch(void* const* d_in, const int* in_sizes, int n_in,
                              void* d_out, int out_size, void* d_ws, size_t ws_size,
                              hipStream_t stream) {
    const float* x   = (const float*)d_in[0];
    const int*   ei  = (const int*)d_in[1];   // [2, E] int32
    const float* W1  = (const float*)d_in[5];
    const float* b1  = (const float*)d_in[6];
    const float* W2  = (const float*)d_in[7];
    const float* b2  = (const float*)d_in[8];
    const float* W3  = (const float*)d_in[9];
    const float* b3  = (const float*)d_in[10];

    const int n_nodes = in_sizes[0] / 3;
    const int n_edges = in_sizes[1] / 2;
    const int* rows = ei;            // edge_index[0]
    const int* cols = ei + n_edges;  // edge_index[1]
    float* out = (float*)d_out;

    const int nb = (n_nodes + TILE - 1) >> SH;

    int chunk = (n_edges + NBLK - 1) / NBLK;
    chunk = (chunk + 3) & ~3;        // keep per-block int4 loads 16B-aligned

    // Fast path ws layout:
    //   x4[N] float4 | packed[E] u32 | partial[SPLITK*N*3] f32
    //   | hist[NBLK*nb] | keyTotal[nb] | keyStart[nb+1]
    const size_t off_x4      = 0;
    const size_t off_packed  = off_x4 + (size_t)n_nodes * 16;
    const size_t off_partial = off_packed + (size_t)n_edges * 4;
    const size_t off_hist    = off_partial + (size_t)SPLITK * n_nodes * 12;
    const size_t off_kt      = off_hist + (size_t)NBLK * nb * 4;
    const size_t off_ks      = off_kt + (size_t)nb * 4;
    const size_t needA       = off_ks + (size_t)(nb + 1) * 4;

    const size_t needB = (size_t)n_edges * 4 + (size_t)NBLK * nb * 4
                       + (size_t)nb * 4 + (size_t)(nb + 1) * 4;
    const bool okA = (ws_size >= needA) && (nb <= MAXNB) && (n_nodes <= (1 << 20));
    const bool okB = (ws_size >= needB) && (nb <= MAXNB) && (n_nodes <= (1 << 20));

    if (okA) {
        float4*   x4       = (float4*)((char*)d_ws + off_x4);
        unsigned* packed   = (unsigned*)((char*)d_ws + off_packed);
        float*    partial  = (float*)((char*)d_ws + off_partial);
        int*      hist     = (int*)((char*)d_ws + off_hist);
        int*      keyTotal = (int*)((char*)d_ws + off_kt);
        int*      keyStart = (int*)((char*)d_ws + off_ks);

        pad_x_kernel<<<2048, 256, 0, stream>>>(x, x4, n_nodes);
        hist_kernel<<<NBLK, THR, 0, stream>>>(cols, hist, nb, chunk, n_edges);
        scan_blocks_kernel<<<nb, NBLK, 0, stream>>>(hist, keyTotal, nb);
        scan_keys_kernel<<<1, 1024, 0, stream>>>(keyTotal, keyStart, nb);
        scatter_kernel<<<NBLK, THR, 0, stream>>>(cols, rows, hist, keyStart,
                                                 packed, nb, chunk, n_edges);
        agg_partial_kernel<<<nb * SPLITK, THR, 0, stream>>>(
            packed, x4, keyStart, partial, n_nodes, nb);
        merge_mlp_kernel<<<(n_nodes + 255) / 256, 256, 0, stream>>>(
            partial, x, W1, b1, W2, b2, W3, b3, out, n_nodes);
    } else if (okB) {
        unsigned* packed = (unsigned*)d_ws;
        int* hist        = (int*)(packed + n_edges);
        int* keyTotal    = hist + (size_t)NBLK * nb;
        int* keyStart    = keyTotal + nb;

        hist_kernel<<<NBLK, THR, 0, stream>>>(cols, hist, nb, chunk, n_edges);
        scan_blocks_kernel<<<nb, NBLK, 0, stream>>>(hist, keyTotal, nb);
        scan_keys_kernel<<<1, 1024, 0, stream>>>(keyTotal, keyStart, nb);
        scatter_kernel<<<NBLK, THR, 0, stream>>>(cols, rows, hist, keyStart,
                                                 packed, nb, chunk, n_edges);
        bucket_agg_mlp_kernel<<<nb, THR, 0, stream>>>(
            packed, x, keyStart, W1, b1, W2, b2, W3, b3, out, n_nodes);
    } else {
        hipMemsetAsync(d_out, 0, (size_t)out_size * sizeof(float), stream);
        edge_scatter_kernel<<<8192, 256, 0, stream>>>(rows, cols, x, out, n_edges);
        node_mlp_kernel<<<(n_nodes + 255) / 256, 256, 0, stream>>>(
            x, W1, b1, W2, b2, W3, b3, out, n_nodes);
    }
}